// Round 2
// baseline (3160.840 us; speedup 1.0000x reference)
//
#include <hip/hip_runtime.h>

#define DD 512          // x feature dim
#define HH 512          // hidden dim
#define KW 1024         // weight row length (D + H)
#define BM 32           // node tile
#define BN 64           // output-j tile
#define KT 32           // K tile
#define XS 36           // padded LDS stride for A tiles (float4-aligned rows, conflict-light)
#define WS 65           // padded LDS stride for W tiles (conflict-free)

__device__ __forceinline__ float sigf(float v)    { return 1.0f / (1.0f + __expf(-v)); }
__device__ __forceinline__ float tanhfast(float v){ return 2.0f / (1.0f + __expf(-2.0f * v)) - 1.0f; }

// ---------------- Leaf level: h-part of xh is zero; gates i,o,u only ----------------
// Writes level-local rows 0..cnt-1 of hw/cw.
__global__ __launch_bounds__(256) void leaf_kernel(
    const float* __restrict__ x,
    const float* __restrict__ Wi, const float* __restrict__ bi,
    const float* __restrict__ Wo, const float* __restrict__ bo,
    const float* __restrict__ Wu, const float* __restrict__ bu,
    float* __restrict__ hw, float* __restrict__ cw,
    int start, int cnt)
{
    __shared__ __align__(16) float XA [KT][XS];
    __shared__ __align__(16) float TWI[KT][WS];
    __shared__ __align__(16) float TWO[KT][WS];
    __shared__ __align__(16) float TWU[KT][WS];

    const int tid = threadIdx.x;
    const int mb  = blockIdx.x * BM;
    const int jb  = blockIdx.y * BN;
    const int tj  = tid & 63;
    const int m0  = (tid >> 6) * 8;

    float ai[8], ao[8], au[8];
    #pragma unroll
    for (int r = 0; r < 8; ++r) { ai[r] = 0.f; ao[r] = 0.f; au[r] = 0.f; }

    for (int kb = 0; kb < DD; kb += KT) {
        // stage A (x) tile transposed: XA[k][m]
        {
            int m  = tid >> 3;
            int k4 = (tid & 7) * 4;
            int gm = mb + m; if (gm >= cnt) gm = cnt - 1;
            const float4 v = *(const float4*)&x[(size_t)(start + gm) * DD + kb + k4];
            XA[k4+0][m] = v.x; XA[k4+1][m] = v.y; XA[k4+2][m] = v.z; XA[k4+3][m] = v.w;
        }
        // stage W tiles transposed: TW*[k][j]  (x half of each weight row)
        for (int e = tid; e < (BN * KT) / 4; e += 256) {
            int jj = e >> 3;
            int k4 = (e & 7) * 4;
            size_t off = (size_t)(jb + jj) * KW + kb + k4;
            float4 vi = *(const float4*)&Wi[off];
            float4 vo = *(const float4*)&Wo[off];
            float4 vu = *(const float4*)&Wu[off];
            TWI[k4+0][jj] = vi.x; TWI[k4+1][jj] = vi.y; TWI[k4+2][jj] = vi.z; TWI[k4+3][jj] = vi.w;
            TWO[k4+0][jj] = vo.x; TWO[k4+1][jj] = vo.y; TWO[k4+2][jj] = vo.z; TWO[k4+3][jj] = vo.w;
            TWU[k4+0][jj] = vu.x; TWU[k4+1][jj] = vu.y; TWU[k4+2][jj] = vu.z; TWU[k4+3][jj] = vu.w;
        }
        __syncthreads();

        #pragma unroll 8
        for (int k = 0; k < KT; ++k) {
            float4 a0 = *(const float4*)&XA[k][m0];
            float4 a1 = *(const float4*)&XA[k][m0 + 4];
            float wi = TWI[k][tj], wo = TWO[k][tj], wu = TWU[k][tj];
            float a[8] = {a0.x, a0.y, a0.z, a0.w, a1.x, a1.y, a1.z, a1.w};
            #pragma unroll
            for (int r = 0; r < 8; ++r) {
                ai[r] = fmaf(a[r], wi, ai[r]);
                ao[r] = fmaf(a[r], wo, ao[r]);
                au[r] = fmaf(a[r], wu, au[r]);
            }
        }
        __syncthreads();
    }

    const int j = jb + tj;
    const float bii = bi[j], boo = bo[j], buu = bu[j];
    #pragma unroll
    for (int r = 0; r < 8; ++r) {
        int gm = mb + m0 + r;
        if (gm < cnt) {
            float pi = sigf(ai[r] + bii);
            float po = sigf(ao[r] + boo);
            float pu = tanhfast(au[r] + buu);
            float cn = pi * pu;
            float hn = po * tanhfast(cn);
            size_t idx = (size_t)gm * HH + j;
            hw[idx] = hn;
            cw[idx] = cn;
        }
    }
}

// ---------------- Internal level: full 5-gate update with children h/c ----------------
// Children of local node gm live at local rows 2*gm, 2*gm+1 of hc/cc.
// Writes level-local rows 0..cnt-1 of hw/cw.
__global__ __launch_bounds__(256) void level_kernel(
    const float* __restrict__ x,
    const float* __restrict__ Wi, const float* __restrict__ bi,
    const float* __restrict__ Wf, const float* __restrict__ bf,
    const float* __restrict__ Wo, const float* __restrict__ bo,
    const float* __restrict__ Wu, const float* __restrict__ bu,
    const float* __restrict__ hc, const float* __restrict__ cc,
    float* __restrict__ hw, float* __restrict__ cw,
    int start, int cnt)
{
    __shared__ __align__(16) float A1 [KT][XS];   // phase1: x tile; phase2: h_l tile
    __shared__ __align__(16) float A2 [KT][XS];   // phase2: h_r tile
    __shared__ __align__(16) float TWI[KT][WS];
    __shared__ __align__(16) float TWF[KT][WS];
    __shared__ __align__(16) float TWO[KT][WS];
    __shared__ __align__(16) float TWU[KT][WS];

    const int tid = threadIdx.x;
    const int mb  = blockIdx.x * BM;
    const int jb  = blockIdx.y * BN;
    const int tj  = tid & 63;
    const int m0  = (tid >> 6) * 8;

    float ai[8], af[8], ao[8], au[8];
    #pragma unroll
    for (int r = 0; r < 8; ++r) { ai[r] = 0.f; af[r] = 0.f; ao[r] = 0.f; au[r] = 0.f; }

    // ---- phase 1: x contribution (weight cols 0..511), shared across i,f,o,u ----
    for (int kb = 0; kb < DD; kb += KT) {
        {
            int m  = tid >> 3;
            int k4 = (tid & 7) * 4;
            int gm = mb + m; if (gm >= cnt) gm = cnt - 1;
            const float4 v = *(const float4*)&x[(size_t)(start + gm) * DD + kb + k4];
            A1[k4+0][m] = v.x; A1[k4+1][m] = v.y; A1[k4+2][m] = v.z; A1[k4+3][m] = v.w;
        }
        for (int e = tid; e < (BN * KT) / 4; e += 256) {
            int jj = e >> 3;
            int k4 = (e & 7) * 4;
            size_t off = (size_t)(jb + jj) * KW + kb + k4;
            float4 vi = *(const float4*)&Wi[off];
            float4 vf = *(const float4*)&Wf[off];
            float4 vo = *(const float4*)&Wo[off];
            float4 vu = *(const float4*)&Wu[off];
            TWI[k4+0][jj] = vi.x; TWI[k4+1][jj] = vi.y; TWI[k4+2][jj] = vi.z; TWI[k4+3][jj] = vi.w;
            TWF[k4+0][jj] = vf.x; TWF[k4+1][jj] = vf.y; TWF[k4+2][jj] = vf.z; TWF[k4+3][jj] = vf.w;
            TWO[k4+0][jj] = vo.x; TWO[k4+1][jj] = vo.y; TWO[k4+2][jj] = vo.z; TWO[k4+3][jj] = vo.w;
            TWU[k4+0][jj] = vu.x; TWU[k4+1][jj] = vu.y; TWU[k4+2][jj] = vu.z; TWU[k4+3][jj] = vu.w;
        }
        __syncthreads();

        #pragma unroll 8
        for (int k = 0; k < KT; ++k) {
            float4 a0 = *(const float4*)&A1[k][m0];
            float4 a1 = *(const float4*)&A1[k][m0 + 4];
            float wi = TWI[k][tj], wf = TWF[k][tj], wo = TWO[k][tj], wu = TWU[k][tj];
            float a[8] = {a0.x, a0.y, a0.z, a0.w, a1.x, a1.y, a1.z, a1.w};
            #pragma unroll
            for (int r = 0; r < 8; ++r) {
                ai[r] = fmaf(a[r], wi, ai[r]);
                af[r] = fmaf(a[r], wf, af[r]);
                ao[r] = fmaf(a[r], wo, ao[r]);
                au[r] = fmaf(a[r], wu, au[r]);
            }
        }
        __syncthreads();
    }

    // fork the shared x-part of the f gate into left/right accumulators
    float afl[8], afr[8];
    #pragma unroll
    for (int r = 0; r < 8; ++r) { afl[r] = af[r]; afr[r] = af[r]; }

    // ---- phase 2: h contribution (weight cols 512..1023) ----
    for (int kb = 0; kb < HH; kb += KT) {
        {
            int m  = tid >> 3;
            int k4 = (tid & 7) * 4;
            int gm = mb + m; if (gm >= cnt) gm = cnt - 1;
            size_t rowl = (size_t)(2 * gm) * HH + kb + k4;
            const float4 vl = *(const float4*)&hc[rowl];
            const float4 vr = *(const float4*)&hc[rowl + HH];
            A1[k4+0][m] = vl.x; A1[k4+1][m] = vl.y; A1[k4+2][m] = vl.z; A1[k4+3][m] = vl.w;
            A2[k4+0][m] = vr.x; A2[k4+1][m] = vr.y; A2[k4+2][m] = vr.z; A2[k4+3][m] = vr.w;
        }
        for (int e = tid; e < (BN * KT) / 4; e += 256) {
            int jj = e >> 3;
            int k4 = (e & 7) * 4;
            size_t off = (size_t)(jb + jj) * KW + DD + kb + k4;
            float4 vi = *(const float4*)&Wi[off];
            float4 vf = *(const float4*)&Wf[off];
            float4 vo = *(const float4*)&Wo[off];
            float4 vu = *(const float4*)&Wu[off];
            TWI[k4+0][jj] = vi.x; TWI[k4+1][jj] = vi.y; TWI[k4+2][jj] = vi.z; TWI[k4+3][jj] = vi.w;
            TWF[k4+0][jj] = vf.x; TWF[k4+1][jj] = vf.y; TWF[k4+2][jj] = vf.z; TWF[k4+3][jj] = vf.w;
            TWO[k4+0][jj] = vo.x; TWO[k4+1][jj] = vo.y; TWO[k4+2][jj] = vo.z; TWO[k4+3][jj] = vo.w;
            TWU[k4+0][jj] = vu.x; TWU[k4+1][jj] = vu.y; TWU[k4+2][jj] = vu.z; TWU[k4+3][jj] = vu.w;
        }
        __syncthreads();

        #pragma unroll 8
        for (int k = 0; k < KT; ++k) {
            float4 l0 = *(const float4*)&A1[k][m0];
            float4 l1 = *(const float4*)&A1[k][m0 + 4];
            float4 r0 = *(const float4*)&A2[k][m0];
            float4 r1 = *(const float4*)&A2[k][m0 + 4];
            float wi = TWI[k][tj], wf = TWF[k][tj], wo = TWO[k][tj], wu = TWU[k][tj];
            float hl[8] = {l0.x, l0.y, l0.z, l0.w, l1.x, l1.y, l1.z, l1.w};
            float hr[8] = {r0.x, r0.y, r0.z, r0.w, r1.x, r1.y, r1.z, r1.w};
            #pragma unroll
            for (int r = 0; r < 8; ++r) {
                float hs = hl[r] + hr[r];
                ai[r]  = fmaf(hs,    wi, ai[r]);
                ao[r]  = fmaf(hs,    wo, ao[r]);
                au[r]  = fmaf(hs,    wu, au[r]);
                afl[r] = fmaf(hl[r], wf, afl[r]);
                afr[r] = fmaf(hr[r], wf, afr[r]);
            }
        }
        __syncthreads();
    }

    const int j = jb + tj;
    const float bii = bi[j], bff = bf[j], boo = bo[j], buu = bu[j];
    #pragma unroll
    for (int r = 0; r < 8; ++r) {
        int gm = mb + m0 + r;
        if (gm < cnt) {
            size_t cidx = (size_t)(2 * gm) * HH + j;
            float c_l = cc[cidx];
            float c_r = cc[cidx + HH];
            float pi  = sigf(ai[r]  + bii);
            float pfl = sigf(afl[r] + bff);
            float pfr = sigf(afr[r] + bff);
            float po  = sigf(ao[r]  + boo);
            float pu  = tanhfast(au[r] + buu);
            float cn  = pi * pu + pfl * c_l + pfr * c_r;
            float hn  = po * tanhfast(cn);
            size_t idx = (size_t)gm * HH + j;
            hw[idx] = hn;
            cw[idx] = cn;
        }
    }
}

// ---------------- Copy root h/c to output ----------------
__global__ void copy_out_kernel(const float* __restrict__ h, const float* __restrict__ c,
                                float* __restrict__ out)
{
    int i = blockIdx.x * blockDim.x + threadIdx.x;
    if (i < HH)            out[i] = h[i];
    else if (i < 2 * HH)   out[i] = c[i - HH];
}

extern "C" void kernel_launch(void* const* d_in, const int* in_sizes, int n_in,
                              void* d_out, int out_size, void* d_ws, size_t ws_size,
                              hipStream_t stream) {
    const float* x  = (const float*)d_in[0];
    const float* Wi = (const float*)d_in[1];
    const float* bi = (const float*)d_in[2];
    const float* Wf = (const float*)d_in[3];
    const float* bf = (const float*)d_in[4];
    const float* Wo = (const float*)d_in[5];
    const float* bo = (const float*)d_in[6];
    const float* Wu = (const float*)d_in[7];
    const float* bu = (const float*)d_in[8];
    float* out = (float*)d_out;

    // Ping-pong workspace layout (96 MiB total):
    //   bufA: h/c for up to 16384 nodes (even-distance levels from leaf)
    //   bufB: h/c for up to  8192 nodes (odd-distance levels)
    const size_t NA = (size_t)16384 * HH;   // floats per A array
    const size_t NB = (size_t)8192  * HH;   // floats per B array
    float* hA = (float*)d_ws;
    float* cA = hA + NA;
    float* hB = cA + NA;
    float* cB = hB + NB;

    // leaf level (lvl = 14) -> bufA
    {
        int start = (1 << 14) - 1;
        int cnt   = 1 << 14;
        dim3 grid((cnt + BM - 1) / BM, HH / BN);
        leaf_kernel<<<grid, 256, 0, stream>>>(x, Wi, bi, Wo, bo, Wu, bu, hA, cA, start, cnt);
    }

    // internal levels, root last; ping-pong child/write buffers
    float *hc = hA, *ccp = cA;   // child (just-written) buffers
    float *hw = hB, *cwp = cB;   // write buffers
    for (int lvl = 13; lvl >= 0; --lvl) {
        int start = (1 << lvl) - 1;
        int cnt   = 1 << lvl;
        dim3 grid((cnt + BM - 1) / BM, HH / BN);
        level_kernel<<<grid, 256, 0, stream>>>(x, Wi, bi, Wf, bf, Wo, bo, Wu, bu,
                                               hc, ccp, hw, cwp, start, cnt);
        float* t;
        t = hc; hc = hw; hw = t;
        t = ccp; ccp = cwp; cwp = t;
    }

    // after the loop, hc/ccp point at the buffers holding level 0 (the root)
    copy_out_kernel<<<4, 256, 0, stream>>>(hc, ccp, out);
}

// Round 3
// 845.669 us; speedup vs baseline: 3.7377x; 3.7377x over previous
//
#include <hip/hip_runtime.h>

typedef __attribute__((ext_vector_type(8))) short bf16x8;
typedef __attribute__((ext_vector_type(4))) float f32x4;

#define HHE 512   // hidden/feature row length (elements)

__device__ __forceinline__ unsigned short rne_bf16(float f) {
    union { float f; unsigned u; } v; v.f = f;
    unsigned r = v.u + 0x7FFFu + ((v.u >> 16) & 1u);
    return (unsigned short)(r >> 16);
}
__device__ __forceinline__ float bf2f(unsigned short s) {
    union { unsigned u; float f; } v; v.u = ((unsigned)s) << 16; return v.f;
}
__device__ __forceinline__ float sigf(float v)   { return 1.0f / (1.0f + __expf(-v)); }
__device__ __forceinline__ float tanhf_(float v) { return 2.0f / (1.0f + __expf(-2.0f * v)) - 1.0f; }

// ---------- one-time: pack 4 gate weight matrices (512x1024 f32) into bf16 MFMA
// B-fragment order: [gate][jtile(32)][kstep(32)][lane(64)][8 elems] ----------
__global__ __launch_bounds__(256) void pack_w(
    const float* __restrict__ Wi, const float* __restrict__ Wf,
    const float* __restrict__ Wo, const float* __restrict__ Wu,
    unsigned short* __restrict__ wp)
{
    int t    = blockIdx.x * 256 + threadIdx.x;   // 0..262143
    int lane = t & 63;
    int fid  = t >> 6;                            // 0..4095
    int ks   = fid & 31;
    int jt   = (fid >> 5) & 31;
    int g    = fid >> 10;
    const float* W = (g == 0) ? Wi : (g == 1) ? Wf : (g == 2) ? Wo : Wu;
    int row = jt * 16 + (lane & 15);
    int col = ks * 32 + (lane >> 4) * 8;
    const float* src = W + (size_t)row * 1024 + col;
    float4 f0 = *(const float4*)(src);
    float4 f1 = *(const float4*)(src + 4);
    uint4 o;
    o.x = (unsigned)rne_bf16(f0.x) | ((unsigned)rne_bf16(f0.y) << 16);
    o.y = (unsigned)rne_bf16(f0.z) | ((unsigned)rne_bf16(f0.w) << 16);
    o.z = (unsigned)rne_bf16(f1.x) | ((unsigned)rne_bf16(f1.y) << 16);
    o.w = (unsigned)rne_bf16(f1.z) | ((unsigned)rne_bf16(f1.w) << 16);
    ((uint4*)wp)[t] = o;   // byte offset fid*1024 + lane*16 == t*16
}

// ---------- one-time: x fp32 -> bf16 ----------
__global__ __launch_bounds__(256) void conv_x(const float* __restrict__ x,
                                              unsigned short* __restrict__ xb)
{
    size_t idx = (size_t)blockIdx.x * 256 + threadIdx.x;
    if (idx >= 2097088) return;                   // 32767*512/8
    const float4* p = (const float4*)x + idx * 2;
    float4 f0 = p[0], f1 = p[1];
    uint4 o;
    o.x = (unsigned)rne_bf16(f0.x) | ((unsigned)rne_bf16(f0.y) << 16);
    o.y = (unsigned)rne_bf16(f0.z) | ((unsigned)rne_bf16(f0.w) << 16);
    o.z = (unsigned)rne_bf16(f1.x) | ((unsigned)rne_bf16(f1.y) << 16);
    o.w = (unsigned)rne_bf16(f1.z) | ((unsigned)rne_bf16(f1.w) << 16);
    ((uint4*)xb)[idx] = o;
}

#define MFMA16(a, b, c) __builtin_amdgcn_mfma_f32_16x16x32_bf16(a, b, c, 0, 0, 0)

// ---------- leaf level (cnt=16384): gates i,o,u on x only ----------
__global__ __launch_bounds__(256) void leaf_mfma(
    const unsigned short* __restrict__ xb, const unsigned short* __restrict__ wp,
    const float* __restrict__ bi, const float* __restrict__ bo, const float* __restrict__ bu,
    unsigned short* __restrict__ hw, unsigned short* __restrict__ cw,
    unsigned short* __restrict__ hso,
    int start, int cnt)
{
    const int tid  = threadIdx.x;
    const int lane = tid & 63;
    const int wv   = tid >> 6;
    const int quad = lane >> 4;
    const int ln   = lane & 15;
    const int mb   = blockIdx.x * 64;
    const int jt   = blockIdx.y * 4 + wv;
    const int j    = jt * 16 + ln;

    int row[4];
    #pragma unroll
    for (int t = 0; t < 4; ++t) {
        int r = mb + t * 16 + ln;
        row[t] = (r < cnt) ? r : (cnt - 1);
    }
    const unsigned short* ax[4];
    #pragma unroll
    for (int t = 0; t < 4; ++t) ax[t] = xb + (size_t)(start + row[t]) * HHE + quad * 8;

    // gates: i=0, o=2, u=3 in pack order (f=1 unused at leaf)
    const unsigned short* bwi = wp + ((size_t)(0 * 32 + jt) * 32) * 512 + lane * 8;
    const unsigned short* bwo = wp + ((size_t)(2 * 32 + jt) * 32) * 512 + lane * 8;
    const unsigned short* bwu = wp + ((size_t)(3 * 32 + jt) * 32) * 512 + lane * 8;

    f32x4 zero = {0.f, 0.f, 0.f, 0.f};
    f32x4 acc_i[4], acc_o[4], acc_u[4];
    #pragma unroll
    for (int t = 0; t < 4; ++t) { acc_i[t] = zero; acc_o[t] = zero; acc_u[t] = zero; }

    #pragma unroll 4
    for (int ks = 0; ks < 16; ++ks) {
        bf16x8 a[4];
        #pragma unroll
        for (int t = 0; t < 4; ++t) { a[t] = *(const bf16x8*)ax[t]; ax[t] += 32; }
        bf16x8 b0 = *(const bf16x8*)bwi; bwi += 512;
        bf16x8 b2 = *(const bf16x8*)bwo; bwo += 512;
        bf16x8 b3 = *(const bf16x8*)bwu; bwu += 512;
        #pragma unroll
        for (int t = 0; t < 4; ++t) {
            acc_i[t] = MFMA16(a[t], b0, acc_i[t]);
            acc_o[t] = MFMA16(a[t], b2, acc_o[t]);
            acc_u[t] = MFMA16(a[t], b3, acc_u[t]);
        }
    }

    const float bij = bi[j], boj = bo[j], buj = bu[j];
    #pragma unroll
    for (int t = 0; t < 4; ++t) {
        const int n0 = mb + t * 16 + quad * 4;
        float hv[4];
        #pragma unroll
        for (int r = 0; r < 4; ++r) {
            const int node = n0 + r;
            float gi = sigf(acc_i[t][r] + bij);
            float go = sigf(acc_o[t][r] + boj);
            float gu = tanhf_(acc_u[t][r] + buj);
            float cnv = gi * gu;
            float hnv = go * tanhf_(cnv);
            hv[r] = hnv;
            if (node < cnt) {
                size_t oix = (size_t)node * HHE + j;
                hw[oix] = rne_bf16(hnv);
                cw[oix] = rne_bf16(cnv);
            }
        }
        if (n0 + 1 < cnt) hso[(size_t)(n0 >> 1) * HHE + j]       = rne_bf16(hv[0] + hv[1]);
        if (n0 + 3 < cnt) hso[(size_t)((n0 >> 1) + 1) * HHE + j] = rne_bf16(hv[2] + hv[3]);
    }
}

// ---------- internal level: 5-gate update, MFMA, no LDS ----------
__global__ __launch_bounds__(256) void level_mfma(
    const unsigned short* __restrict__ xb, const unsigned short* __restrict__ wp,
    const float* __restrict__ bi, const float* __restrict__ bfv,
    const float* __restrict__ bo, const float* __restrict__ bu,
    const unsigned short* __restrict__ hc,   // child h bf16 [2*cnt][512]
    const unsigned short* __restrict__ cc,   // child c bf16 [2*cnt][512]
    const unsigned short* __restrict__ hs,   // hsum bf16 [cnt][512] (from child epilogue)
    unsigned short* __restrict__ hw,
    unsigned short* __restrict__ cw,
    unsigned short* __restrict__ hso,        // parent hsum [cnt/2][512]
    float* __restrict__ f32out,              // root only: h->out[0:512], c->out[512:1024]
    int start, int cnt)
{
    const int tid  = threadIdx.x;
    const int lane = tid & 63;
    const int wv   = tid >> 6;
    const int quad = lane >> 4;
    const int ln   = lane & 15;
    const int mb   = blockIdx.x * 64;
    const int jt   = blockIdx.y * 4 + wv;
    const int j    = jt * 16 + ln;

    int row[4];
    #pragma unroll
    for (int t = 0; t < 4; ++t) {
        int r = mb + t * 16 + ln;
        row[t] = (r < cnt) ? r : (cnt - 1);
    }
    const unsigned short* ax[4];
    #pragma unroll
    for (int t = 0; t < 4; ++t) ax[t] = xb + (size_t)(start + row[t]) * HHE + quad * 8;

    const unsigned short* bw[4];
    #pragma unroll
    for (int g = 0; g < 4; ++g) bw[g] = wp + ((size_t)(g * 32 + jt) * 32) * 512 + lane * 8;

    f32x4 zero = {0.f, 0.f, 0.f, 0.f};
    f32x4 acc_i[4], acc_f[4], acc_o[4], acc_u[4];
    #pragma unroll
    for (int t = 0; t < 4; ++t) { acc_i[t] = zero; acc_f[t] = zero; acc_o[t] = zero; acc_u[t] = zero; }

    // ---- phase 1: x contribution (W cols 0..511), f shared ----
    #pragma unroll 4
    for (int ks = 0; ks < 16; ++ks) {
        bf16x8 a[4];
        #pragma unroll
        for (int t = 0; t < 4; ++t) { a[t] = *(const bf16x8*)ax[t]; ax[t] += 32; }
        bf16x8 b0 = *(const bf16x8*)bw[0]; bw[0] += 512;
        bf16x8 b1 = *(const bf16x8*)bw[1]; bw[1] += 512;
        bf16x8 b2 = *(const bf16x8*)bw[2]; bw[2] += 512;
        bf16x8 b3 = *(const bf16x8*)bw[3]; bw[3] += 512;
        #pragma unroll
        for (int t = 0; t < 4; ++t) {
            acc_i[t] = MFMA16(a[t], b0, acc_i[t]);
            acc_f[t] = MFMA16(a[t], b1, acc_f[t]);
            acc_o[t] = MFMA16(a[t], b2, acc_o[t]);
            acc_u[t] = MFMA16(a[t], b3, acc_u[t]);
        }
    }

    f32x4 acc_fl[4], acc_fr[4];
    #pragma unroll
    for (int t = 0; t < 4; ++t) { acc_fl[t] = acc_f[t]; acc_fr[t] = acc_f[t]; }

    const unsigned short* as[4];
    const unsigned short* al[4];
    const unsigned short* ar[4];
    #pragma unroll
    for (int t = 0; t < 4; ++t) {
        as[t] = hs + (size_t)row[t] * HHE + quad * 8;
        al[t] = hc + (size_t)(2 * row[t]) * HHE + quad * 8;
        ar[t] = al[t] + HHE;
    }

    // ---- phase 2: h contribution (W cols 512..1023); i/o/u use hsum, f uses h_l / h_r ----
    #pragma unroll 2
    for (int ks = 0; ks < 16; ++ks) {
        bf16x8 b0 = *(const bf16x8*)bw[0]; bw[0] += 512;
        bf16x8 b1 = *(const bf16x8*)bw[1]; bw[1] += 512;
        bf16x8 b2 = *(const bf16x8*)bw[2]; bw[2] += 512;
        bf16x8 b3 = *(const bf16x8*)bw[3]; bw[3] += 512;
        bf16x8 s[4];
        #pragma unroll
        for (int t = 0; t < 4; ++t) { s[t] = *(const bf16x8*)as[t]; as[t] += 32; }
        #pragma unroll
        for (int t = 0; t < 4; ++t) {
            acc_i[t] = MFMA16(s[t], b0, acc_i[t]);
            acc_o[t] = MFMA16(s[t], b2, acc_o[t]);
            acc_u[t] = MFMA16(s[t], b3, acc_u[t]);
        }
        bf16x8 l[4];
        #pragma unroll
        for (int t = 0; t < 4; ++t) { l[t] = *(const bf16x8*)al[t]; al[t] += 32; }
        #pragma unroll
        for (int t = 0; t < 4; ++t) acc_fl[t] = MFMA16(l[t], b1, acc_fl[t]);
        bf16x8 rr[4];
        #pragma unroll
        for (int t = 0; t < 4; ++t) { rr[t] = *(const bf16x8*)ar[t]; ar[t] += 32; }
        #pragma unroll
        for (int t = 0; t < 4; ++t) acc_fr[t] = MFMA16(rr[t], b1, acc_fr[t]);
    }

    // ---- epilogue ----
    const float bij = bi[j], bfj = bfv[j], boj = bo[j], buj = bu[j];
    #pragma unroll
    for (int t = 0; t < 4; ++t) {
        const int n0 = mb + t * 16 + quad * 4;
        float hv[4];
        #pragma unroll
        for (int r = 0; r < 4; ++r) {
            const int node = n0 + r;
            const int ncl  = (node < cnt) ? node : (cnt - 1);
            size_t cix = (size_t)(2 * ncl) * HHE + j;
            float cl = bf2f(cc[cix]);
            float cr = bf2f(cc[cix + HHE]);
            float gi  = sigf(acc_i[t][r] + bij);
            float gfl = sigf(acc_fl[t][r] + bfj);
            float gfr = sigf(acc_fr[t][r] + bfj);
            float go  = sigf(acc_o[t][r] + boj);
            float gu  = tanhf_(acc_u[t][r] + buj);
            float cnv = gi * gu + gfl * cl + gfr * cr;
            float hnv = go * tanhf_(cnv);
            hv[r] = hnv;
            if (node < cnt) {
                size_t oix = (size_t)node * HHE + j;
                hw[oix] = rne_bf16(hnv);
                cw[oix] = rne_bf16(cnv);
                if (f32out) {
                    f32out[(size_t)node * 1024 + j]       = hnv;
                    f32out[(size_t)node * 1024 + 512 + j] = cnv;
                }
            }
        }
        if (n0 + 1 < cnt) hso[(size_t)(n0 >> 1) * HHE + j]       = rne_bf16(hv[0] + hv[1]);
        if (n0 + 3 < cnt) hso[(size_t)((n0 >> 1) + 1) * HHE + j] = rne_bf16(hv[2] + hv[3]);
    }
}

extern "C" void kernel_launch(void* const* d_in, const int* in_sizes, int n_in,
                              void* d_out, int out_size, void* d_ws, size_t ws_size,
                              hipStream_t stream) {
    const float* x  = (const float*)d_in[0];
    const float* Wi = (const float*)d_in[1];
    const float* bi = (const float*)d_in[2];
    const float* Wf = (const float*)d_in[3];
    const float* bf = (const float*)d_in[4];
    const float* Wo = (const float*)d_in[5];
    const float* bo = (const float*)d_in[6];
    const float* Wu = (const float*)d_in[7];
    const float* bu = (const float*)d_in[8];
    float* out = (float*)d_out;

    // workspace layout (ushort units), total 100,662,272 B
    unsigned short* xb  = (unsigned short*)d_ws;          // 16,776,704  x bf16
    unsigned short* wp  = xb  + 16776704;                 //  2,097,152  packed W bf16
    unsigned short* hA  = wp  + 2097152;                  //  8,388,608  h ping (16384 rows)
    unsigned short* hB  = hA  + 8388608;                  //  4,194,304  h pong ( 8192 rows)
    unsigned short* hs1 = hB  + 4194304;                  //  4,194,304  hsum ( 8192 rows)
    unsigned short* hs2 = hs1 + 4194304;                  //  2,097,152  hsum ( 4096 rows)
    unsigned short* cA  = hs2 + 2097152;                  //  8,388,608  c ping bf16
    unsigned short* cB  = cA  + 8388608;                  //  4,194,304  c pong bf16

    pack_w<<<1024, 256, 0, stream>>>(Wi, Wf, Wo, Wu, wp);
    conv_x<<<8192, 256, 0, stream>>>(x, xb);

    // leaf (lvl 14): writes hA/cA + hsum for lvl 13 into hs1
    leaf_mfma<<<dim3(256, 8), 256, 0, stream>>>(xb, wp, bi, bo, bu, hA, cA, hs1, 16383, 16384);

    for (int lvl = 13; lvl >= 0; --lvl) {
        int cnt   = 1 << lvl;
        int start = cnt - 1;
        const unsigned short *hc, *cc, *hs;
        unsigned short *hw, *cw, *hso;
        if (lvl & 1) { hc = hA; cc = cA; hs = hs1; hw = hB; cw = cB; hso = hs2; }
        else         { hc = hB; cc = cB; hs = hs2; hw = hA; cw = cA; hso = hs1; }
        float* f32out = (lvl == 0) ? out : nullptr;
        dim3 grid((cnt + 63) / 64, 8);
        level_mfma<<<grid, 256, 0, stream>>>(xb, wp, bi, bf, bo, bu,
                                             hc, cc, hs, hw, cw, hso, f32out,
                                             start, cnt);
    }
}

// Round 4
// 786.981 us; speedup vs baseline: 4.0164x; 1.0746x over previous
//
#include <hip/hip_runtime.h>
#include <hip/hip_cooperative_groups.h>

namespace cg = cooperative_groups;

typedef __attribute__((ext_vector_type(8))) short bf16x8;
typedef __attribute__((ext_vector_type(4))) float f32x4;

#define HHE 512

__device__ __forceinline__ unsigned short rne_bf16(float f) {
    union { float f; unsigned u; } v; v.f = f;
    unsigned r = v.u + 0x7FFFu + ((v.u >> 16) & 1u);
    return (unsigned short)(r >> 16);
}
__device__ __forceinline__ float bf2f(unsigned short s) {
    union { unsigned u; float f; } v; v.u = ((unsigned)s) << 16; return v.f;
}
__device__ __forceinline__ float sigf(float v)   { return 1.0f / (1.0f + __expf(-v)); }
__device__ __forceinline__ float tanhf_(float v) { return 2.0f / (1.0f + __expf(-2.0f * v)) - 1.0f; }

#define MFMA16(a, b, c) __builtin_amdgcn_mfma_f32_16x16x32_bf16(a, b, c, 0, 0, 0)

#define GLOAD_LDS16(g, l) \
    __builtin_amdgcn_global_load_lds((const __attribute__((address_space(1))) void*)(g), \
                                     (__attribute__((address_space(3))) void*)(l), 16, 0, 0)

// ---------- one-time: pack 4 gate weight matrices into bf16 MFMA B-fragment order
// [gate][jtile(32)][kstep(32)][lane(64)][8] ----------
__global__ __launch_bounds__(256) void pack_w(
    const float* __restrict__ Wi, const float* __restrict__ Wf,
    const float* __restrict__ Wo, const float* __restrict__ Wu,
    unsigned short* __restrict__ wp)
{
    int t    = blockIdx.x * 256 + threadIdx.x;
    int lane = t & 63;
    int fid  = t >> 6;
    int ks   = fid & 31;
    int jt   = (fid >> 5) & 31;
    int g    = fid >> 10;
    const float* W = (g == 0) ? Wi : (g == 1) ? Wf : (g == 2) ? Wo : Wu;
    int row = jt * 16 + (lane & 15);
    int col = ks * 32 + (lane >> 4) * 8;
    const float* src = W + (size_t)row * 1024 + col;
    float4 f0 = *(const float4*)(src);
    float4 f1 = *(const float4*)(src + 4);
    uint4 o;
    o.x = (unsigned)rne_bf16(f0.x) | ((unsigned)rne_bf16(f0.y) << 16);
    o.y = (unsigned)rne_bf16(f0.z) | ((unsigned)rne_bf16(f0.w) << 16);
    o.z = (unsigned)rne_bf16(f1.x) | ((unsigned)rne_bf16(f1.y) << 16);
    o.w = (unsigned)rne_bf16(f1.z) | ((unsigned)rne_bf16(f1.w) << 16);
    ((uint4*)wp)[t] = o;
}

// ---------- one-time: x fp32 -> bf16 ----------
__global__ __launch_bounds__(256) void conv_x(const float* __restrict__ x,
                                              unsigned short* __restrict__ xb)
{
    size_t idx = (size_t)blockIdx.x * 256 + threadIdx.x;
    if (idx >= 2097088) return;
    const float4* p = (const float4*)x + idx * 2;
    float4 f0 = p[0], f1 = p[1];
    uint4 o;
    o.x = (unsigned)rne_bf16(f0.x) | ((unsigned)rne_bf16(f0.y) << 16);
    o.y = (unsigned)rne_bf16(f0.z) | ((unsigned)rne_bf16(f0.w) << 16);
    o.z = (unsigned)rne_bf16(f1.x) | ((unsigned)rne_bf16(f1.y) << 16);
    o.w = (unsigned)rne_bf16(f1.z) | ((unsigned)rne_bf16(f1.w) << 16);
    ((uint4*)xb)[idx] = o;
}

// ---------- leaf level (unchanged, register path) ----------
__global__ __launch_bounds__(256) void leaf_mfma(
    const unsigned short* __restrict__ xb, const unsigned short* __restrict__ wp,
    const float* __restrict__ bi, const float* __restrict__ bo, const float* __restrict__ bu,
    unsigned short* __restrict__ hw, unsigned short* __restrict__ cw,
    unsigned short* __restrict__ hso,
    int start, int cnt)
{
    const int tid  = threadIdx.x;
    const int lane = tid & 63;
    const int wv   = tid >> 6;
    const int quad = lane >> 4;
    const int ln   = lane & 15;
    const int mb   = blockIdx.x * 64;
    const int jt   = blockIdx.y * 4 + wv;
    const int j    = jt * 16 + ln;

    int row[4];
    #pragma unroll
    for (int t = 0; t < 4; ++t) {
        int r = mb + t * 16 + ln;
        row[t] = (r < cnt) ? r : (cnt - 1);
    }
    const unsigned short* ax[4];
    #pragma unroll
    for (int t = 0; t < 4; ++t) ax[t] = xb + (size_t)(start + row[t]) * HHE + quad * 8;

    const unsigned short* bwi = wp + ((size_t)(0 * 32 + jt) * 32) * 512 + lane * 8;
    const unsigned short* bwo = wp + ((size_t)(2 * 32 + jt) * 32) * 512 + lane * 8;
    const unsigned short* bwu = wp + ((size_t)(3 * 32 + jt) * 32) * 512 + lane * 8;

    f32x4 zero = {0.f, 0.f, 0.f, 0.f};
    f32x4 acc_i[4], acc_o[4], acc_u[4];
    #pragma unroll
    for (int t = 0; t < 4; ++t) { acc_i[t] = zero; acc_o[t] = zero; acc_u[t] = zero; }

    #pragma unroll 4
    for (int ks = 0; ks < 16; ++ks) {
        bf16x8 a[4];
        #pragma unroll
        for (int t = 0; t < 4; ++t) { a[t] = *(const bf16x8*)ax[t]; ax[t] += 32; }
        bf16x8 b0 = *(const bf16x8*)bwi; bwi += 512;
        bf16x8 b2 = *(const bf16x8*)bwo; bwo += 512;
        bf16x8 b3 = *(const bf16x8*)bwu; bwu += 512;
        #pragma unroll
        for (int t = 0; t < 4; ++t) {
            acc_i[t] = MFMA16(a[t], b0, acc_i[t]);
            acc_o[t] = MFMA16(a[t], b2, acc_o[t]);
            acc_u[t] = MFMA16(a[t], b3, acc_u[t]);
        }
    }

    const float bij = bi[j], boj = bo[j], buj = bu[j];
    #pragma unroll
    for (int t = 0; t < 4; ++t) {
        const int n0 = mb + t * 16 + quad * 4;
        float hv[4];
        #pragma unroll
        for (int r = 0; r < 4; ++r) {
            const int node = n0 + r;
            float gi = sigf(acc_i[t][r] + bij);
            float go = sigf(acc_o[t][r] + boj);
            float gu = tanhf_(acc_u[t][r] + buj);
            float cnv = gi * gu;
            float hnv = go * tanhf_(cnv);
            hv[r] = hnv;
            if (node < cnt) {
                size_t oix = (size_t)node * HHE + j;
                hw[oix] = rne_bf16(hnv);
                cw[oix] = rne_bf16(cnv);
            }
        }
        if (n0 + 1 < cnt) hso[(size_t)(n0 >> 1) * HHE + j]       = rne_bf16(hv[0] + hv[1]);
        if (n0 + 3 < cnt) hso[(size_t)((n0 >> 1) + 1) * HHE + j] = rne_bf16(hv[2] + hv[3]);
    }
}

// ---------- big internal levels (cnt multiple of 64): LDS-staged, double-buffered ----------
__global__ __launch_bounds__(256, 2) void level_v2(
    const unsigned short* __restrict__ xb, const unsigned short* __restrict__ wp,
    const float* __restrict__ bi, const float* __restrict__ bfv,
    const float* __restrict__ bo, const float* __restrict__ bu,
    const unsigned short* __restrict__ hc, const unsigned short* __restrict__ cc,
    const unsigned short* __restrict__ hs,
    unsigned short* __restrict__ hw, unsigned short* __restrict__ cw,
    unsigned short* __restrict__ hso,
    int start, int cnt)
{
    // LDS: [buf 2][stream 3][64 rows][32 elems] bf16 = 24 KiB
    __shared__ __align__(16) unsigned short SH[2 * 3 * 2048];

    const int tid  = threadIdx.x;
    const int lane = tid & 63;
    const int wv   = tid >> 6;
    const int q    = lane >> 4;
    const int ln   = lane & 15;
    const int wm   = wv & 1;       // m half (32 rows)
    const int wj   = wv >> 1;      // j half (2 jtiles)
    const int mb   = blockIdx.x * 64;
    const int jt0  = blockIdx.y * 4 + wj * 2;

    // stage-side lane mapping: lane l -> row l>>2 of the wave's 16-row chunk,
    // LDS slot l&3, holding global chunk (l&3) ^ ((l>>3)&3)  [xor swizzle]
    const int srow   = lane >> 2;
    const int gchunk = (lane & 3) ^ ((lane >> 3) & 3);
    const int stage_row = mb + wv * 16 + srow;            // global node-local row

    // read-side swizzle: per-lane constant chunk permutation
    const int rdoff = ((q ^ ((ln >> 1) & 3)) * 8);        // elem offset within 32-elem row

    const unsigned short* wpl = wp + (size_t)lane * 8;

    f32x4 zero = {0.f, 0.f, 0.f, 0.f};
    f32x4 acc_i[2][2], acc_f[2][2], acc_o[2][2], acc_u[2][2];
    #pragma unroll
    for (int t = 0; t < 2; ++t)
        #pragma unroll
        for (int ji = 0; ji < 2; ++ji) {
            acc_i[t][ji] = zero; acc_f[t][ji] = zero;
            acc_o[t][ji] = zero; acc_u[t][ji] = zero;
        }

    // ---------------- phase 1: x ----------------
    // stage ks=0 into buf 0 (stream 0)
    {
        const unsigned short* g = xb + (size_t)(start + stage_row) * HHE + gchunk * 8;
        GLOAD_LDS16(g, &SH[(0 * 3 + 0) * 2048 + wv * 512]);
    }
    __syncthreads();

    for (int ks = 0; ks < 16; ++ks) {
        const int cur = ks & 1;
        if (ks < 15) {
            const unsigned short* g = xb + (size_t)(start + stage_row) * HHE + (ks + 1) * 32 + gchunk * 8;
            GLOAD_LDS16(g, &SH[((cur ^ 1) * 3 + 0) * 2048 + wv * 512]);
        }
        bf16x8 bfr[4][2];
        #pragma unroll
        for (int g = 0; g < 4; ++g)
            #pragma unroll
            for (int ji = 0; ji < 2; ++ji)
                bfr[g][ji] = *(const bf16x8*)(wpl + ((size_t)((g * 32 + jt0 + ji) * 32 + ks)) * 512);
        bf16x8 a0 = *(const bf16x8*)&SH[(cur * 3 + 0) * 2048 + (wm * 32 + 0 + ln) * 32 + rdoff];
        bf16x8 a1 = *(const bf16x8*)&SH[(cur * 3 + 0) * 2048 + (wm * 32 + 16 + ln) * 32 + rdoff];
        #pragma unroll
        for (int ji = 0; ji < 2; ++ji) {
            acc_i[0][ji] = MFMA16(a0, bfr[0][ji], acc_i[0][ji]);
            acc_i[1][ji] = MFMA16(a1, bfr[0][ji], acc_i[1][ji]);
            acc_f[0][ji] = MFMA16(a0, bfr[1][ji], acc_f[0][ji]);
            acc_f[1][ji] = MFMA16(a1, bfr[1][ji], acc_f[1][ji]);
            acc_o[0][ji] = MFMA16(a0, bfr[2][ji], acc_o[0][ji]);
            acc_o[1][ji] = MFMA16(a1, bfr[2][ji], acc_o[1][ji]);
            acc_u[0][ji] = MFMA16(a0, bfr[3][ji], acc_u[0][ji]);
            acc_u[1][ji] = MFMA16(a1, bfr[3][ji], acc_u[1][ji]);
        }
        __syncthreads();
    }

    // fork f
    f32x4 acc_fl[2][2], acc_fr[2][2];
    #pragma unroll
    for (int t = 0; t < 2; ++t)
        #pragma unroll
        for (int ji = 0; ji < 2; ++ji) { acc_fl[t][ji] = acc_f[t][ji]; acc_fr[t][ji] = acc_f[t][ji]; }

    // ---------------- phase 2: hsum / h_l / h_r ----------------
    {
        const unsigned short* gs = hs + (size_t)stage_row * HHE + gchunk * 8;
        const unsigned short* gl = hc + ((size_t)(2 * stage_row)) * HHE + gchunk * 8;
        GLOAD_LDS16(gs, &SH[(0 * 3 + 0) * 2048 + wv * 512]);
        GLOAD_LDS16(gl, &SH[(0 * 3 + 1) * 2048 + wv * 512]);
        GLOAD_LDS16(gl + HHE, &SH[(0 * 3 + 2) * 2048 + wv * 512]);
    }
    __syncthreads();

    for (int ks = 0; ks < 16; ++ks) {
        const int cur = ks & 1;
        if (ks < 15) {
            const unsigned short* gs = hs + (size_t)stage_row * HHE + (ks + 1) * 32 + gchunk * 8;
            const unsigned short* gl = hc + ((size_t)(2 * stage_row)) * HHE + (ks + 1) * 32 + gchunk * 8;
            GLOAD_LDS16(gs, &SH[((cur ^ 1) * 3 + 0) * 2048 + wv * 512]);
            GLOAD_LDS16(gl, &SH[((cur ^ 1) * 3 + 1) * 2048 + wv * 512]);
            GLOAD_LDS16(gl + HHE, &SH[((cur ^ 1) * 3 + 2) * 2048 + wv * 512]);
        }
        bf16x8 bfr[4][2];
        #pragma unroll
        for (int g = 0; g < 4; ++g)
            #pragma unroll
            for (int ji = 0; ji < 2; ++ji)
                bfr[g][ji] = *(const bf16x8*)(wpl + ((size_t)((g * 32 + jt0 + ji) * 32 + 16 + ks)) * 512);
        bf16x8 s0 = *(const bf16x8*)&SH[(cur * 3 + 0) * 2048 + (wm * 32 + 0 + ln) * 32 + rdoff];
        bf16x8 s1 = *(const bf16x8*)&SH[(cur * 3 + 0) * 2048 + (wm * 32 + 16 + ln) * 32 + rdoff];
        bf16x8 l0 = *(const bf16x8*)&SH[(cur * 3 + 1) * 2048 + (wm * 32 + 0 + ln) * 32 + rdoff];
        bf16x8 l1 = *(const bf16x8*)&SH[(cur * 3 + 1) * 2048 + (wm * 32 + 16 + ln) * 32 + rdoff];
        bf16x8 r0 = *(const bf16x8*)&SH[(cur * 3 + 2) * 2048 + (wm * 32 + 0 + ln) * 32 + rdoff];
        bf16x8 r1 = *(const bf16x8*)&SH[(cur * 3 + 2) * 2048 + (wm * 32 + 16 + ln) * 32 + rdoff];
        #pragma unroll
        for (int ji = 0; ji < 2; ++ji) {
            acc_i[0][ji]  = MFMA16(s0, bfr[0][ji], acc_i[0][ji]);
            acc_i[1][ji]  = MFMA16(s1, bfr[0][ji], acc_i[1][ji]);
            acc_o[0][ji]  = MFMA16(s0, bfr[2][ji], acc_o[0][ji]);
            acc_o[1][ji]  = MFMA16(s1, bfr[2][ji], acc_o[1][ji]);
            acc_u[0][ji]  = MFMA16(s0, bfr[3][ji], acc_u[0][ji]);
            acc_u[1][ji]  = MFMA16(s1, bfr[3][ji], acc_u[1][ji]);
            acc_fl[0][ji] = MFMA16(l0, bfr[1][ji], acc_fl[0][ji]);
            acc_fl[1][ji] = MFMA16(l1, bfr[1][ji], acc_fl[1][ji]);
            acc_fr[0][ji] = MFMA16(r0, bfr[1][ji], acc_fr[0][ji]);
            acc_fr[1][ji] = MFMA16(r1, bfr[1][ji], acc_fr[1][ji]);
        }
        __syncthreads();
    }

    // ---------------- epilogue ----------------
    #pragma unroll
    for (int ji = 0; ji < 2; ++ji) {
        const int jj = (jt0 + ji) * 16 + ln;
        const float bij = bi[jj], bfj = bfv[jj], boj = bo[jj], buj = bu[jj];
        #pragma unroll
        for (int t = 0; t < 2; ++t) {
            const int n0 = mb + wm * 32 + t * 16 + q * 4;
            float hv[4];
            #pragma unroll
            for (int r = 0; r < 4; ++r) {
                const int node = n0 + r;
                size_t cix = (size_t)(2 * node) * HHE + jj;
                float cl = bf2f(cc[cix]);
                float cr = bf2f(cc[cix + HHE]);
                float gi  = sigf(acc_i[t][ji][r] + bij);
                float gfl = sigf(acc_fl[t][ji][r] + bfj);
                float gfr = sigf(acc_fr[t][ji][r] + bfj);
                float go  = sigf(acc_o[t][ji][r] + boj);
                float gu  = tanhf_(acc_u[t][ji][r] + buj);
                float cnv = gi * gu + gfl * cl + gfr * cr;
                float hnv = go * tanhf_(cnv);
                hv[r] = hnv;
                size_t oix = (size_t)node * HHE + jj;
                hw[oix] = rne_bf16(hnv);
                cw[oix] = rne_bf16(cnv);
            }
            hso[(size_t)(n0 >> 1) * HHE + jj]       = rne_bf16(hv[0] + hv[1]);
            hso[(size_t)((n0 >> 1) + 1) * HHE + jj] = rne_bf16(hv[2] + hv[3]);
        }
    }
}

// ---------- fallback per-level register kernel (also root epilogue path) ----------
__global__ __launch_bounds__(256) void level_reg(
    const unsigned short* __restrict__ xb, const unsigned short* __restrict__ wp,
    const float* __restrict__ bi, const float* __restrict__ bfv,
    const float* __restrict__ bo, const float* __restrict__ bu,
    const unsigned short* __restrict__ hc, const unsigned short* __restrict__ cc,
    const unsigned short* __restrict__ hs,
    unsigned short* __restrict__ hw, unsigned short* __restrict__ cw,
    unsigned short* __restrict__ hso,
    float* __restrict__ f32out,
    int start, int cnt)
{
    const int tid  = threadIdx.x;
    const int lane = tid & 63;
    const int wv   = tid >> 6;
    const int quad = lane >> 4;
    const int ln   = lane & 15;
    const int mb   = blockIdx.x * 64;
    const int jt   = blockIdx.y * 4 + wv;
    const int j    = jt * 16 + ln;

    int row[4];
    #pragma unroll
    for (int t = 0; t < 4; ++t) {
        int r = mb + t * 16 + ln;
        row[t] = (r < cnt) ? r : (cnt - 1);
    }
    const unsigned short* ax[4];
    #pragma unroll
    for (int t = 0; t < 4; ++t) ax[t] = xb + (size_t)(start + row[t]) * HHE + quad * 8;

    const unsigned short* bw[4];
    #pragma unroll
    for (int g = 0; g < 4; ++g) bw[g] = wp + ((size_t)(g * 32 + jt) * 32) * 512 + lane * 8;

    f32x4 zero = {0.f, 0.f, 0.f, 0.f};
    f32x4 acc_i[4], acc_f[4], acc_o[4], acc_u[4];
    #pragma unroll
    for (int t = 0; t < 4; ++t) { acc_i[t] = zero; acc_f[t] = zero; acc_o[t] = zero; acc_u[t] = zero; }

    #pragma unroll 4
    for (int ks = 0; ks < 16; ++ks) {
        bf16x8 a[4];
        #pragma unroll
        for (int t = 0; t < 4; ++t) { a[t] = *(const bf16x8*)ax[t]; ax[t] += 32; }
        bf16x8 b0 = *(const bf16x8*)bw[0]; bw[0] += 512;
        bf16x8 b1 = *(const bf16x8*)bw[1]; bw[1] += 512;
        bf16x8 b2 = *(const bf16x8*)bw[2]; bw[2] += 512;
        bf16x8 b3 = *(const bf16x8*)bw[3]; bw[3] += 512;
        #pragma unroll
        for (int t = 0; t < 4; ++t) {
            acc_i[t] = MFMA16(a[t], b0, acc_i[t]);
            acc_f[t] = MFMA16(a[t], b1, acc_f[t]);
            acc_o[t] = MFMA16(a[t], b2, acc_o[t]);
            acc_u[t] = MFMA16(a[t], b3, acc_u[t]);
        }
    }

    f32x4 acc_fl[4], acc_fr[4];
    #pragma unroll
    for (int t = 0; t < 4; ++t) { acc_fl[t] = acc_f[t]; acc_fr[t] = acc_f[t]; }

    const unsigned short* as[4];
    const unsigned short* al[4];
    const unsigned short* ar[4];
    #pragma unroll
    for (int t = 0; t < 4; ++t) {
        as[t] = hs + (size_t)row[t] * HHE + quad * 8;
        al[t] = hc + (size_t)(2 * row[t]) * HHE + quad * 8;
        ar[t] = al[t] + HHE;
    }

    #pragma unroll 2
    for (int ks = 0; ks < 16; ++ks) {
        bf16x8 b0 = *(const bf16x8*)bw[0]; bw[0] += 512;
        bf16x8 b1 = *(const bf16x8*)bw[1]; bw[1] += 512;
        bf16x8 b2 = *(const bf16x8*)bw[2]; bw[2] += 512;
        bf16x8 b3 = *(const bf16x8*)bw[3]; bw[3] += 512;
        bf16x8 s[4];
        #pragma unroll
        for (int t = 0; t < 4; ++t) { s[t] = *(const bf16x8*)as[t]; as[t] += 32; }
        #pragma unroll
        for (int t = 0; t < 4; ++t) {
            acc_i[t] = MFMA16(s[t], b0, acc_i[t]);
            acc_o[t] = MFMA16(s[t], b2, acc_o[t]);
            acc_u[t] = MFMA16(s[t], b3, acc_u[t]);
        }
        bf16x8 l[4];
        #pragma unroll
        for (int t = 0; t < 4; ++t) { l[t] = *(const bf16x8*)al[t]; al[t] += 32; }
        #pragma unroll
        for (int t = 0; t < 4; ++t) acc_fl[t] = MFMA16(l[t], b1, acc_fl[t]);
        bf16x8 rr[4];
        #pragma unroll
        for (int t = 0; t < 4; ++t) { rr[t] = *(const bf16x8*)ar[t]; ar[t] += 32; }
        #pragma unroll
        for (int t = 0; t < 4; ++t) acc_fr[t] = MFMA16(rr[t], b1, acc_fr[t]);
    }

    const float bij = bi[j], bfj = bfv[j], boj = bo[j], buj = bu[j];
    #pragma unroll
    for (int t = 0; t < 4; ++t) {
        const int n0 = mb + t * 16 + quad * 4;
        float hv[4];
        #pragma unroll
        for (int r = 0; r < 4; ++r) {
            const int node = n0 + r;
            const int ncl  = (node < cnt) ? node : (cnt - 1);
            size_t cix = (size_t)(2 * ncl) * HHE + j;
            float cl = bf2f(cc[cix]);
            float cr = bf2f(cc[cix + HHE]);
            float gi  = sigf(acc_i[t][r] + bij);
            float gfl = sigf(acc_fl[t][r] + bfj);
            float gfr = sigf(acc_fr[t][r] + bfj);
            float go  = sigf(acc_o[t][r] + boj);
            float gu  = tanhf_(acc_u[t][r] + buj);
            float cnv = gi * gu + gfl * cl + gfr * cr;
            float hnv = go * tanhf_(cnv);
            hv[r] = hnv;
            if (node < cnt) {
                size_t oix = (size_t)node * HHE + j;
                hw[oix] = rne_bf16(hnv);
                cw[oix] = rne_bf16(cnv);
                if (f32out) {
                    f32out[(size_t)node * 1024 + j]       = hnv;
                    f32out[(size_t)node * 1024 + 512 + j] = cnv;
                }
            }
        }
        if (n0 + 1 < cnt) hso[(size_t)(n0 >> 1) * HHE + j]       = rne_bf16(hv[0] + hv[1]);
        if (n0 + 3 < cnt) hso[(size_t)((n0 >> 1) + 1) * HHE + j] = rne_bf16(hv[2] + hv[3]);
    }
}

// ---------- fused tail: levels 9..0 in one cooperative kernel ----------
__global__ __launch_bounds__(256) void tail_coop(
    const unsigned short* xb, const unsigned short* wp,
    const float* bi, const float* bfv, const float* bo, const float* bu,
    unsigned short* hA, unsigned short* cA,
    unsigned short* hB, unsigned short* cB,
    unsigned short* hs1, unsigned short* hs2,
    float* out)
{
    cg::grid_group grid = cg::this_grid();
    const int tid  = threadIdx.x;
    const int lane = tid & 63;
    const int wv   = tid >> 6;
    const int q    = lane >> 4;
    const int ln   = lane & 15;
    const int blk  = blockIdx.x;
    const int mblk = blk >> 3;
    const int jblk = blk & 7;
    const int jt   = jblk * 4 + wv;
    const int j    = jt * 16 + ln;

    for (int lvl = 9; lvl >= 0; --lvl) {
        const int cnt   = 1 << lvl;
        const int start = cnt - 1;
        const unsigned short *hc, *cc, *hs;
        unsigned short *hw, *cw, *hso;
        if (lvl & 1) { hc = hA; cc = cA; hs = hs1; hw = hB; cw = cB; hso = hs2; }
        else         { hc = hB; cc = cB; hs = hs2; hw = hA; cw = cA; hso = hs1; }
        const int mchunks = (cnt + 15) >> 4;
        if (mblk < mchunks) {
            const int mb16 = mblk * 16;
            int mrow = mb16 + ln; if (mrow >= cnt) mrow = cnt - 1;

            const unsigned short* ax = xb + (size_t)(start + mrow) * HHE + q * 8;
            const unsigned short* b0p = wp + ((size_t)(0 * 32 + jt) * 32) * 512 + lane * 8;
            const unsigned short* b1p = wp + ((size_t)(1 * 32 + jt) * 32) * 512 + lane * 8;
            const unsigned short* b2p = wp + ((size_t)(2 * 32 + jt) * 32) * 512 + lane * 8;
            const unsigned short* b3p = wp + ((size_t)(3 * 32 + jt) * 32) * 512 + lane * 8;

            f32x4 zero = {0.f, 0.f, 0.f, 0.f};
            f32x4 ai = zero, af = zero, ao = zero, au = zero;
            #pragma unroll 4
            for (int ks = 0; ks < 16; ++ks) {
                bf16x8 a = *(const bf16x8*)ax; ax += 32;
                bf16x8 b0 = *(const bf16x8*)b0p; b0p += 512;
                bf16x8 b1 = *(const bf16x8*)b1p; b1p += 512;
                bf16x8 b2 = *(const bf16x8*)b2p; b2p += 512;
                bf16x8 b3 = *(const bf16x8*)b3p; b3p += 512;
                ai = MFMA16(a, b0, ai);
                af = MFMA16(a, b1, af);
                ao = MFMA16(a, b2, ao);
                au = MFMA16(a, b3, au);
            }
            f32x4 fl = af, fr = af;
            const unsigned short* as = hs + (size_t)mrow * HHE + q * 8;
            const unsigned short* al = hc + (size_t)(2 * mrow) * HHE + q * 8;
            const unsigned short* ar = al + HHE;
            #pragma unroll 4
            for (int ks = 0; ks < 16; ++ks) {
                bf16x8 s  = *(const bf16x8*)as; as += 32;
                bf16x8 l  = *(const bf16x8*)al; al += 32;
                bf16x8 rr = *(const bf16x8*)ar; ar += 32;
                bf16x8 b0 = *(const bf16x8*)b0p; b0p += 512;
                bf16x8 b1 = *(const bf16x8*)b1p; b1p += 512;
                bf16x8 b2 = *(const bf16x8*)b2p; b2p += 512;
                bf16x8 b3 = *(const bf16x8*)b3p; b3p += 512;
                ai = MFMA16(s, b0, ai);
                ao = MFMA16(s, b2, ao);
                au = MFMA16(s, b3, au);
                fl = MFMA16(l, b1, fl);
                fr = MFMA16(rr, b1, fr);
            }

            const float bij = bi[j], bfj = bfv[j], boj = bo[j], buj = bu[j];
            const int n0 = mb16 + q * 4;
            float hv[4];
            #pragma unroll
            for (int r = 0; r < 4; ++r) {
                const int node = n0 + r;
                const int ncl  = (node < cnt) ? node : (cnt - 1);
                size_t cix = (size_t)(2 * ncl) * HHE + j;
                float cl = bf2f(cc[cix]);
                float cr = bf2f(cc[cix + HHE]);
                float gi  = sigf(ai[r] + bij);
                float gfl = sigf(fl[r] + bfj);
                float gfr = sigf(fr[r] + bfj);
                float go  = sigf(ao[r] + boj);
                float gu  = tanhf_(au[r] + buj);
                float cnv = gi * gu + gfl * cl + gfr * cr;
                float hnv = go * tanhf_(cnv);
                hv[r] = hnv;
                if (node < cnt) {
                    size_t oix = (size_t)node * HHE + j;
                    hw[oix] = rne_bf16(hnv);
                    cw[oix] = rne_bf16(cnv);
                    if (lvl == 0) {
                        out[j]       = hnv;
                        out[512 + j] = cnv;
                    }
                }
            }
            if (n0 + 1 < cnt) hso[(size_t)(n0 >> 1) * HHE + j]       = rne_bf16(hv[0] + hv[1]);
            if (n0 + 3 < cnt) hso[(size_t)((n0 >> 1) + 1) * HHE + j] = rne_bf16(hv[2] + hv[3]);
        }
        if (lvl) grid.sync();
    }
}

extern "C" void kernel_launch(void* const* d_in, const int* in_sizes, int n_in,
                              void* d_out, int out_size, void* d_ws, size_t ws_size,
                              hipStream_t stream) {
    const float* x  = (const float*)d_in[0];
    const float* Wi = (const float*)d_in[1];
    const float* bi = (const float*)d_in[2];
    const float* Wf = (const float*)d_in[3];
    const float* bf = (const float*)d_in[4];
    const float* Wo = (const float*)d_in[5];
    const float* bo = (const float*)d_in[6];
    const float* Wu = (const float*)d_in[7];
    const float* bu = (const float*)d_in[8];
    float* out = (float*)d_out;

    unsigned short* xb  = (unsigned short*)d_ws;          // x bf16
    unsigned short* wp  = xb  + 16776704;                 // packed W bf16
    unsigned short* hA  = wp  + 2097152;                  // h ping (16384 rows)
    unsigned short* hB  = hA  + 8388608;                  // h pong ( 8192 rows)
    unsigned short* hs1 = hB  + 4194304;                  // hsum ( 8192 rows)
    unsigned short* hs2 = hs1 + 4194304;                  // hsum ( 4096 rows)
    unsigned short* cA  = hs2 + 2097152;                  // c ping
    unsigned short* cB  = cA  + 8388608;                  // c pong

    pack_w<<<1024, 256, 0, stream>>>(Wi, Wf, Wo, Wu, wp);
    conv_x<<<8192, 256, 0, stream>>>(x, xb);

    leaf_mfma<<<dim3(256, 8), 256, 0, stream>>>(xb, wp, bi, bo, bu, hA, cA, hs1, 16383, 16384);

    // big levels via LDS kernel
    for (int lvl = 13; lvl >= 10; --lvl) {
        int cnt   = 1 << lvl;
        int start = cnt - 1;
        const unsigned short *hc, *cc, *hs;
        unsigned short *hw, *cw, *hso;
        if (lvl & 1) { hc = hA; cc = cA; hs = hs1; hw = hB; cw = cB; hso = hs2; }
        else         { hc = hB; cc = cB; hs = hs2; hw = hA; cw = cA; hso = hs1; }
        dim3 grid(cnt / 64, 8);
        level_v2<<<grid, 256, 0, stream>>>(xb, wp, bi, bf, bo, bu,
                                           hc, cc, hs, hw, cw, hso, start, cnt);
    }

    // fused cooperative tail for levels 9..0 (fallback: per-level register kernels)
    {
        void* args[] = { (void*)&xb, (void*)&wp, (void*)&bi, (void*)&bf, (void*)&bo, (void*)&bu,
                         (void*)&hA, (void*)&cA, (void*)&hB, (void*)&cB,
                         (void*)&hs1, (void*)&hs2, (void*)&out };
        hipError_t err = hipLaunchCooperativeKernel((void*)tail_coop, dim3(256), dim3(256),
                                                    args, 0, stream);
        if (err != hipSuccess) {
            for (int lvl = 9; lvl >= 0; --lvl) {
                int cnt   = 1 << lvl;
                int start = cnt - 1;
                const unsigned short *hc, *cc, *hs;
                unsigned short *hw, *cw, *hso;
                if (lvl & 1) { hc = hA; cc = cA; hs = hs1; hw = hB; cw = cB; hso = hs2; }
                else         { hc = hB; cc = cB; hs = hs2; hw = hA; cw = cA; hso = hs1; }
                float* f32out = (lvl == 0) ? out : nullptr;
                dim3 grid((cnt + 63) / 64, 8);
                level_reg<<<grid, 256, 0, stream>>>(xb, wp, bi, bf, bo, bu,
                                                    hc, cc, hs, hw, cw, hso, f32out,
                                                    start, cnt);
            }
        }
    }
}

// Round 6
// 679.011 us; speedup vs baseline: 4.6551x; 1.1590x over previous
//
#include <hip/hip_runtime.h>

typedef __attribute__((ext_vector_type(8))) short bf16x8;
typedef __attribute__((ext_vector_type(4))) float f32x4;

#define HHE 512
#define TAIL_NBLK 256

__device__ __forceinline__ unsigned short rne_bf16(float f) {
    union { float f; unsigned u; } v; v.f = f;
    unsigned r = v.u + 0x7FFFu + ((v.u >> 16) & 1u);
    return (unsigned short)(r >> 16);
}
__device__ __forceinline__ float bf2f(unsigned short s) {
    union { unsigned u; float f; } v; v.u = ((unsigned)s) << 16; return v.f;
}
__device__ __forceinline__ float sigf(float v)   { return 1.0f / (1.0f + __expf(-v)); }
__device__ __forceinline__ float tanhf_(float v) { return 2.0f / (1.0f + __expf(-2.0f * v)) - 1.0f; }

#define MFMA16(a, b, c) __builtin_amdgcn_mfma_f32_16x16x32_bf16(a, b, c, 0, 0, 0)

#define GLOAD_LDS16(g, l) \
    __builtin_amdgcn_global_load_lds((const __attribute__((address_space(1))) void*)(g), \
                                     (__attribute__((address_space(3))) void*)(l), 16, 0, 0)

// ---- device-scope coherent helpers (compiler-generated sc0/sc1 + waitcnt) ----
__device__ __forceinline__ bf16x8 load8_agent(const unsigned short* p) {
    const unsigned* q = (const unsigned*)p;     // 16B-aligned by construction
    union { unsigned u[4]; bf16x8 b; } x;
    x.u[0] = __hip_atomic_load(q + 0, __ATOMIC_RELAXED, __HIP_MEMORY_SCOPE_AGENT);
    x.u[1] = __hip_atomic_load(q + 1, __ATOMIC_RELAXED, __HIP_MEMORY_SCOPE_AGENT);
    x.u[2] = __hip_atomic_load(q + 2, __ATOMIC_RELAXED, __HIP_MEMORY_SCOPE_AGENT);
    x.u[3] = __hip_atomic_load(q + 3, __ATOMIC_RELAXED, __HIP_MEMORY_SCOPE_AGENT);
    return x.b;
}
__device__ __forceinline__ unsigned load_u32_agent(const unsigned short* p) {
    return __hip_atomic_load((const unsigned*)p, __ATOMIC_RELAXED, __HIP_MEMORY_SCOPE_AGENT);
}
// lane-paired bf16 store: lanes ln / ln^1 hold columns j / j^1; even lane
// stores one packed dword. Caller guarantees the condition is pair-uniform.
__device__ __forceinline__ void store_bf16_pair(unsigned short* rowbase, int j, float v) {
    unsigned mine  = rne_bf16(v);
    unsigned other = __shfl_xor(mine, 1, 64);
    if (!(j & 1)) {
        unsigned packed = mine | (other << 16);
        __hip_atomic_store((unsigned*)(rowbase + j), packed,
                           __ATOMIC_RELAXED, __HIP_MEMORY_SCOPE_AGENT);
    }
}

// ---------- one-time: pack 4 gate weight matrices into bf16 MFMA B-fragment order
// [gate][jtile(32)][kstep(32)][lane(64)][8] ----------
__global__ __launch_bounds__(256) void pack_w(
    const float* __restrict__ Wi, const float* __restrict__ Wf,
    const float* __restrict__ Wo, const float* __restrict__ Wu,
    unsigned short* __restrict__ wp)
{
    int t    = blockIdx.x * 256 + threadIdx.x;
    int lane = t & 63;
    int fid  = t >> 6;
    int ks   = fid & 31;
    int jt   = (fid >> 5) & 31;
    int g    = fid >> 10;
    const float* W = (g == 0) ? Wi : (g == 1) ? Wf : (g == 2) ? Wo : Wu;
    int row = jt * 16 + (lane & 15);
    int col = ks * 32 + (lane >> 4) * 8;
    const float* src = W + (size_t)row * 1024 + col;
    float4 f0 = *(const float4*)(src);
    float4 f1 = *(const float4*)(src + 4);
    uint4 o;
    o.x = (unsigned)rne_bf16(f0.x) | ((unsigned)rne_bf16(f0.y) << 16);
    o.y = (unsigned)rne_bf16(f0.z) | ((unsigned)rne_bf16(f0.w) << 16);
    o.z = (unsigned)rne_bf16(f1.x) | ((unsigned)rne_bf16(f1.y) << 16);
    o.w = (unsigned)rne_bf16(f1.z) | ((unsigned)rne_bf16(f1.w) << 16);
    ((uint4*)wp)[t] = o;
}

// ---------- one-time: x fp32 -> bf16 ----------
__global__ __launch_bounds__(256) void conv_x(const float* __restrict__ x,
                                              unsigned short* __restrict__ xb)
{
    size_t idx = (size_t)blockIdx.x * 256 + threadIdx.x;
    if (idx >= 2097088) return;
    const float4* p = (const float4*)x + idx * 2;
    float4 f0 = p[0], f1 = p[1];
    uint4 o;
    o.x = (unsigned)rne_bf16(f0.x) | ((unsigned)rne_bf16(f0.y) << 16);
    o.y = (unsigned)rne_bf16(f0.z) | ((unsigned)rne_bf16(f0.w) << 16);
    o.z = (unsigned)rne_bf16(f1.x) | ((unsigned)rne_bf16(f1.y) << 16);
    o.w = (unsigned)rne_bf16(f1.z) | ((unsigned)rne_bf16(f1.w) << 16);
    ((uint4*)xb)[idx] = o;
}

// ---------- leaf level (register path, unchanged) ----------
__global__ __launch_bounds__(256) void leaf_mfma(
    const unsigned short* __restrict__ xb, const unsigned short* __restrict__ wp,
    const float* __restrict__ bi, const float* __restrict__ bo, const float* __restrict__ bu,
    unsigned short* __restrict__ hw, unsigned short* __restrict__ cw,
    unsigned short* __restrict__ hso,
    int start, int cnt)
{
    const int tid  = threadIdx.x;
    const int lane = tid & 63;
    const int wv   = tid >> 6;
    const int quad = lane >> 4;
    const int ln   = lane & 15;
    const int mb   = blockIdx.x * 64;
    const int jt   = blockIdx.y * 4 + wv;
    const int j    = jt * 16 + ln;

    int row[4];
    #pragma unroll
    for (int t = 0; t < 4; ++t) {
        int r = mb + t * 16 + ln;
        row[t] = (r < cnt) ? r : (cnt - 1);
    }
    const unsigned short* ax[4];
    #pragma unroll
    for (int t = 0; t < 4; ++t) ax[t] = xb + (size_t)(start + row[t]) * HHE + quad * 8;

    const unsigned short* bwi = wp + ((size_t)(0 * 32 + jt) * 32) * 512 + lane * 8;
    const unsigned short* bwo = wp + ((size_t)(2 * 32 + jt) * 32) * 512 + lane * 8;
    const unsigned short* bwu = wp + ((size_t)(3 * 32 + jt) * 32) * 512 + lane * 8;

    f32x4 zero = {0.f, 0.f, 0.f, 0.f};
    f32x4 acc_i[4], acc_o[4], acc_u[4];
    #pragma unroll
    for (int t = 0; t < 4; ++t) { acc_i[t] = zero; acc_o[t] = zero; acc_u[t] = zero; }

    #pragma unroll 4
    for (int ks = 0; ks < 16; ++ks) {
        bf16x8 a[4];
        #pragma unroll
        for (int t = 0; t < 4; ++t) { a[t] = *(const bf16x8*)ax[t]; ax[t] += 32; }
        bf16x8 b0 = *(const bf16x8*)bwi; bwi += 512;
        bf16x8 b2 = *(const bf16x8*)bwo; bwo += 512;
        bf16x8 b3 = *(const bf16x8*)bwu; bwu += 512;
        #pragma unroll
        for (int t = 0; t < 4; ++t) {
            acc_i[t] = MFMA16(a[t], b0, acc_i[t]);
            acc_o[t] = MFMA16(a[t], b2, acc_o[t]);
            acc_u[t] = MFMA16(a[t], b3, acc_u[t]);
        }
    }

    const float bij = bi[j], boj = bo[j], buj = bu[j];
    #pragma unroll
    for (int t = 0; t < 4; ++t) {
        const int n0 = mb + t * 16 + quad * 4;
        float hv[4];
        #pragma unroll
        for (int r = 0; r < 4; ++r) {
            const int node = n0 + r;
            float gi = sigf(acc_i[t][r] + bij);
            float go = sigf(acc_o[t][r] + boj);
            float gu = tanhf_(acc_u[t][r] + buj);
            float cnv = gi * gu;
            float hnv = go * tanhf_(cnv);
            hv[r] = hnv;
            if (node < cnt) {
                size_t oix = (size_t)node * HHE + j;
                hw[oix] = rne_bf16(hnv);
                cw[oix] = rne_bf16(cnv);
            }
        }
        if (n0 + 1 < cnt) hso[(size_t)(n0 >> 1) * HHE + j]       = rne_bf16(hv[0] + hv[1]);
        if (n0 + 3 < cnt) hso[(size_t)((n0 >> 1) + 1) * HHE + j] = rne_bf16(hv[2] + hv[3]);
    }
}

// ---------- big internal levels (cnt multiple of 64): LDS-staged, double-buffered ----------
__global__ __launch_bounds__(256, 2) void level_v2(
    const unsigned short* __restrict__ xb, const unsigned short* __restrict__ wp,
    const float* __restrict__ bi, const float* __restrict__ bfv,
    const float* __restrict__ bo, const float* __restrict__ bu,
    const unsigned short* __restrict__ hc, const unsigned short* __restrict__ cc,
    const unsigned short* __restrict__ hs,
    unsigned short* __restrict__ hw, unsigned short* __restrict__ cw,
    unsigned short* __restrict__ hso,
    int start, int cnt)
{
    __shared__ __align__(16) unsigned short SH[2 * 3 * 2048];

    const int tid  = threadIdx.x;
    const int lane = tid & 63;
    const int wv   = tid >> 6;
    const int q    = lane >> 4;
    const int ln   = lane & 15;
    const int wm   = wv & 1;
    const int wj   = wv >> 1;
    const int mb   = blockIdx.x * 64;
    const int jt0  = blockIdx.y * 4 + wj * 2;

    const int srow   = lane >> 2;
    const int gchunk = (lane & 3) ^ ((lane >> 3) & 3);
    const int stage_row = mb + wv * 16 + srow;
    const int rdoff = ((q ^ ((ln >> 1) & 3)) * 8);

    const unsigned short* wpl = wp + (size_t)lane * 8;

    f32x4 zero = {0.f, 0.f, 0.f, 0.f};
    f32x4 acc_i[2][2], acc_f[2][2], acc_o[2][2], acc_u[2][2];
    #pragma unroll
    for (int t = 0; t < 2; ++t)
        #pragma unroll
        for (int ji = 0; ji < 2; ++ji) {
            acc_i[t][ji] = zero; acc_f[t][ji] = zero;
            acc_o[t][ji] = zero; acc_u[t][ji] = zero;
        }

    {
        const unsigned short* g = xb + (size_t)(start + stage_row) * HHE + gchunk * 8;
        GLOAD_LDS16(g, &SH[(0 * 3 + 0) * 2048 + wv * 512]);
    }
    __syncthreads();

    for (int ks = 0; ks < 16; ++ks) {
        const int cur = ks & 1;
        if (ks < 15) {
            const unsigned short* g = xb + (size_t)(start + stage_row) * HHE + (ks + 1) * 32 + gchunk * 8;
            GLOAD_LDS16(g, &SH[((cur ^ 1) * 3 + 0) * 2048 + wv * 512]);
        }
        bf16x8 bfr[4][2];
        #pragma unroll
        for (int g = 0; g < 4; ++g)
            #pragma unroll
            for (int ji = 0; ji < 2; ++ji)
                bfr[g][ji] = *(const bf16x8*)(wpl + ((size_t)((g * 32 + jt0 + ji) * 32 + ks)) * 512);
        bf16x8 a0 = *(const bf16x8*)&SH[(cur * 3 + 0) * 2048 + (wm * 32 + 0 + ln) * 32 + rdoff];
        bf16x8 a1 = *(const bf16x8*)&SH[(cur * 3 + 0) * 2048 + (wm * 32 + 16 + ln) * 32 + rdoff];
        #pragma unroll
        for (int ji = 0; ji < 2; ++ji) {
            acc_i[0][ji] = MFMA16(a0, bfr[0][ji], acc_i[0][ji]);
            acc_i[1][ji] = MFMA16(a1, bfr[0][ji], acc_i[1][ji]);
            acc_f[0][ji] = MFMA16(a0, bfr[1][ji], acc_f[0][ji]);
            acc_f[1][ji] = MFMA16(a1, bfr[1][ji], acc_f[1][ji]);
            acc_o[0][ji] = MFMA16(a0, bfr[2][ji], acc_o[0][ji]);
            acc_o[1][ji] = MFMA16(a1, bfr[2][ji], acc_o[1][ji]);
            acc_u[0][ji] = MFMA16(a0, bfr[3][ji], acc_u[0][ji]);
            acc_u[1][ji] = MFMA16(a1, bfr[3][ji], acc_u[1][ji]);
        }
        __syncthreads();
    }

    f32x4 acc_fl[2][2], acc_fr[2][2];
    #pragma unroll
    for (int t = 0; t < 2; ++t)
        #pragma unroll
        for (int ji = 0; ji < 2; ++ji) { acc_fl[t][ji] = acc_f[t][ji]; acc_fr[t][ji] = acc_f[t][ji]; }

    {
        const unsigned short* gs = hs + (size_t)stage_row * HHE + gchunk * 8;
        const unsigned short* gl = hc + ((size_t)(2 * stage_row)) * HHE + gchunk * 8;
        GLOAD_LDS16(gs, &SH[(0 * 3 + 0) * 2048 + wv * 512]);
        GLOAD_LDS16(gl, &SH[(0 * 3 + 1) * 2048 + wv * 512]);
        GLOAD_LDS16(gl + HHE, &SH[(0 * 3 + 2) * 2048 + wv * 512]);
    }
    __syncthreads();

    for (int ks = 0; ks < 16; ++ks) {
        const int cur = ks & 1;
        if (ks < 15) {
            const unsigned short* gs = hs + (size_t)stage_row * HHE + (ks + 1) * 32 + gchunk * 8;
            const unsigned short* gl = hc + ((size_t)(2 * stage_row)) * HHE + (ks + 1) * 32 + gchunk * 8;
            GLOAD_LDS16(gs, &SH[((cur ^ 1) * 3 + 0) * 2048 + wv * 512]);
            GLOAD_LDS16(gl, &SH[((cur ^ 1) * 3 + 1) * 2048 + wv * 512]);
            GLOAD_LDS16(gl + HHE, &SH[((cur ^ 1) * 3 + 2) * 2048 + wv * 512]);
        }
        bf16x8 bfr[4][2];
        #pragma unroll
        for (int g = 0; g < 4; ++g)
            #pragma unroll
            for (int ji = 0; ji < 2; ++ji)
                bfr[g][ji] = *(const bf16x8*)(wpl + ((size_t)((g * 32 + jt0 + ji) * 32 + 16 + ks)) * 512);
        bf16x8 s0 = *(const bf16x8*)&SH[(cur * 3 + 0) * 2048 + (wm * 32 + 0 + ln) * 32 + rdoff];
        bf16x8 s1 = *(const bf16x8*)&SH[(cur * 3 + 0) * 2048 + (wm * 32 + 16 + ln) * 32 + rdoff];
        bf16x8 l0 = *(const bf16x8*)&SH[(cur * 3 + 1) * 2048 + (wm * 32 + 0 + ln) * 32 + rdoff];
        bf16x8 l1 = *(const bf16x8*)&SH[(cur * 3 + 1) * 2048 + (wm * 32 + 16 + ln) * 32 + rdoff];
        bf16x8 r0 = *(const bf16x8*)&SH[(cur * 3 + 2) * 2048 + (wm * 32 + 0 + ln) * 32 + rdoff];
        bf16x8 r1 = *(const bf16x8*)&SH[(cur * 3 + 2) * 2048 + (wm * 32 + 16 + ln) * 32 + rdoff];
        #pragma unroll
        for (int ji = 0; ji < 2; ++ji) {
            acc_i[0][ji]  = MFMA16(s0, bfr[0][ji], acc_i[0][ji]);
            acc_i[1][ji]  = MFMA16(s1, bfr[0][ji], acc_i[1][ji]);
            acc_o[0][ji]  = MFMA16(s0, bfr[2][ji], acc_o[0][ji]);
            acc_o[1][ji]  = MFMA16(s1, bfr[2][ji], acc_o[1][ji]);
            acc_u[0][ji]  = MFMA16(s0, bfr[3][ji], acc_u[0][ji]);
            acc_u[1][ji]  = MFMA16(s1, bfr[3][ji], acc_u[1][ji]);
            acc_fl[0][ji] = MFMA16(l0, bfr[1][ji], acc_fl[0][ji]);
            acc_fl[1][ji] = MFMA16(l1, bfr[1][ji], acc_fl[1][ji]);
            acc_fr[0][ji] = MFMA16(r0, bfr[1][ji], acc_fr[0][ji]);
            acc_fr[1][ji] = MFMA16(r1, bfr[1][ji], acc_fr[1][ji]);
        }
        __syncthreads();
    }

    #pragma unroll
    for (int ji = 0; ji < 2; ++ji) {
        const int jj = (jt0 + ji) * 16 + ln;
        const float bij = bi[jj], bfj = bfv[jj], boj = bo[jj], buj = bu[jj];
        #pragma unroll
        for (int t = 0; t < 2; ++t) {
            const int n0 = mb + wm * 32 + t * 16 + q * 4;
            float hv[4];
            #pragma unroll
            for (int r = 0; r < 4; ++r) {
                const int node = n0 + r;
                size_t cix = (size_t)(2 * node) * HHE + jj;
                float cl = bf2f(cc[cix]);
                float cr = bf2f(cc[cix + HHE]);
                float gi  = sigf(acc_i[t][ji][r] + bij);
                float gfl = sigf(acc_fl[t][ji][r] + bfj);
                float gfr = sigf(acc_fr[t][ji][r] + bfj);
                float go  = sigf(acc_o[t][ji][r] + boj);
                float gu  = tanhf_(acc_u[t][ji][r] + buj);
                float cnv = gi * gu + gfl * cl + gfr * cr;
                float hnv = go * tanhf_(cnv);
                hv[r] = hnv;
                size_t oix = (size_t)node * HHE + jj;
                hw[oix] = rne_bf16(hnv);
                cw[oix] = rne_bf16(cnv);
            }
            hso[(size_t)(n0 >> 1) * HHE + jj]       = rne_bf16(hv[0] + hv[1]);
            hso[(size_t)((n0 >> 1) + 1) * HHE + jj] = rne_bf16(hv[2] + hv[3]);
        }
    }
}

// ---------- fused tail (levels 9..0): persistent grid, fence-free barrier,
// agent-scope relaxed atomics for inter-level data only ----------
__global__ __launch_bounds__(256) void tail_sync(
    const unsigned short* __restrict__ xb, const unsigned short* __restrict__ wp,
    const float* __restrict__ bi, const float* __restrict__ bfv,
    const float* __restrict__ bo, const float* __restrict__ bu,
    unsigned short* hA, unsigned short* cA,
    unsigned short* hB, unsigned short* cB,
    unsigned short* hs1, unsigned short* hs2,
    unsigned* bar, float* out)
{
    const int tid  = threadIdx.x;
    const int lane = tid & 63;
    const int wv   = tid >> 6;
    const int q    = lane >> 4;
    const int ln   = lane & 15;
    const int blk  = blockIdx.x;
    const int mblk = blk >> 3;
    const int jblk = blk & 7;
    const int jt   = jblk * 4 + wv;
    const int j    = jt * 16 + ln;

    const unsigned short* bW[4];
    #pragma unroll
    for (int g = 0; g < 4; ++g) bW[g] = wp + ((size_t)(g * 32 + jt) * 32) * 512 + lane * 8;
    const float bij = bi[j], bfj = bfv[j], boj = bo[j], buj = bu[j];

    for (int lvl = 9; lvl >= 0; --lvl) {
        const int cnt   = 1 << lvl;
        const int start = cnt - 1;
        const unsigned short *hc, *cc, *hs;
        unsigned short *hw, *cw, *hso;
        if (lvl & 1) { hc = hA; cc = cA; hs = hs1; hw = hB; cw = cB; hso = hs2; }
        else         { hc = hB; cc = cB; hs = hs2; hw = hA; cw = cA; hso = hs1; }
        const int mchunks = (cnt + 15) >> 4;
        if (mblk < mchunks) {
            const int mb16 = mblk * 16;
            int mrow = mb16 + ln; if (mrow >= cnt) mrow = cnt - 1;

            // ---- phase 1: x (read-only input, normal cached loads) ----
            const unsigned short* ax = xb + (size_t)(start + mrow) * HHE + q * 8;
            f32x4 zero = {0.f, 0.f, 0.f, 0.f};
            f32x4 ai = zero, af = zero, ao = zero, au = zero;
            #pragma unroll 4
            for (int ks = 0; ks < 16; ++ks) {
                bf16x8 a  = *(const bf16x8*)(ax + ks * 32);
                bf16x8 b0 = *(const bf16x8*)(bW[0] + (size_t)ks * 512);
                bf16x8 b1 = *(const bf16x8*)(bW[1] + (size_t)ks * 512);
                bf16x8 b2 = *(const bf16x8*)(bW[2] + (size_t)ks * 512);
                bf16x8 b3 = *(const bf16x8*)(bW[3] + (size_t)ks * 512);
                ai = MFMA16(a, b0, ai);
                af = MFMA16(a, b1, af);
                ao = MFMA16(a, b2, ao);
                au = MFMA16(a, b3, au);
            }
            f32x4 fl = af, fr = af;

            // ---- phase 2: hsum / h_l / h_r via agent-coherent loads, 12 in flight ----
            const unsigned short* as = hs + (size_t)mrow * HHE + q * 8;
            const unsigned short* al = hc + (size_t)(2 * mrow) * HHE + q * 8;
            const unsigned short* ar = al + HHE;
            #pragma unroll
            for (int g4 = 0; g4 < 4; ++g4) {
                const int kb = g4 * 4;
                bf16x8 S[4], L[4], R[4];
                #pragma unroll
                for (int k = 0; k < 4; ++k) S[k] = load8_agent(as + (kb + k) * 32);
                #pragma unroll
                for (int k = 0; k < 4; ++k) L[k] = load8_agent(al + (kb + k) * 32);
                #pragma unroll
                for (int k = 0; k < 4; ++k) R[k] = load8_agent(ar + (kb + k) * 32);
                #pragma unroll
                for (int k = 0; k < 4; ++k) {
                    const int ks = 16 + kb + k;
                    bf16x8 b0 = *(const bf16x8*)(bW[0] + (size_t)ks * 512);
                    bf16x8 b1 = *(const bf16x8*)(bW[1] + (size_t)ks * 512);
                    bf16x8 b2 = *(const bf16x8*)(bW[2] + (size_t)ks * 512);
                    bf16x8 b3 = *(const bf16x8*)(bW[3] + (size_t)ks * 512);
                    ai = MFMA16(S[k], b0, ai);
                    ao = MFMA16(S[k], b2, ao);
                    au = MFMA16(S[k], b3, au);
                    fl = MFMA16(L[k], b1, fl);
                    fr = MFMA16(R[k], b1, fr);
                }
            }

            // ---- epilogue: agent-coherent c reads + paired h/c/hsum writes ----
            const int n0 = mb16 + q * 4;
            const int ja = j & ~1;      // aligned column for 32-bit pair access
            float hv[4];
            #pragma unroll
            for (int r = 0; r < 4; ++r) {
                const int node = n0 + r;
                const int ncl  = (node < cnt) ? node : (cnt - 1);
                const unsigned short* crow = cc + (size_t)(2 * ncl) * HHE;
                unsigned pl = load_u32_agent(crow + ja);
                unsigned pr = load_u32_agent(crow + HHE + ja);
                float cl = bf2f((unsigned short)((j & 1) ? (pl >> 16) : (pl & 0xffff)));
                float cr = bf2f((unsigned short)((j & 1) ? (pr >> 16) : (pr & 0xffff)));
                float gi  = sigf(ai[r] + bij);
                float gfl = sigf(fl[r] + bfj);
                float gfr = sigf(fr[r] + bfj);
                float go  = sigf(ao[r] + boj);
                float gu  = tanhf_(au[r] + buj);
                float cnv = gi * gu + gfl * cl + gfr * cr;
                float hnv = go * tanhf_(cnv);
                hv[r] = hnv;
                // node<cnt is uniform across the (ln, ln^1) pair
                if (node < cnt) {
                    store_bf16_pair(hw + (size_t)node * HHE, j, hnv);
                    store_bf16_pair(cw + (size_t)node * HHE, j, cnv);
                    if (lvl == 0) {
                        out[j]       = hnv;
                        out[512 + j] = cnv;
                    }
                }
            }
            if (n0 + 1 < cnt) store_bf16_pair(hso + (size_t)(n0 >> 1) * HHE, j, hv[0] + hv[1]);
            if (n0 + 3 < cnt) store_bf16_pair(hso + ((size_t)(n0 >> 1) + 1) * HHE, j, hv[2] + hv[3]);
        }

        // ---- fence-free level barrier (device-scope relaxed atomics) ----
        if (lvl) {
            __builtin_amdgcn_s_waitcnt(0);   // drain outstanding stores
            __syncthreads();                 // block-wide: all stores drained
            if (tid == 0) {
                __hip_atomic_fetch_add(&bar[lvl], 1u, __ATOMIC_RELAXED, __HIP_MEMORY_SCOPE_AGENT);
                while (__hip_atomic_load(&bar[lvl], __ATOMIC_RELAXED, __HIP_MEMORY_SCOPE_AGENT)
                       < (unsigned)TAIL_NBLK)
                    __builtin_amdgcn_s_sleep(2);
            }
            __syncthreads();
        }
    }
}

extern "C" void kernel_launch(void* const* d_in, const int* in_sizes, int n_in,
                              void* d_out, int out_size, void* d_ws, size_t ws_size,
                              hipStream_t stream) {
    const float* x  = (const float*)d_in[0];
    const float* Wi = (const float*)d_in[1];
    const float* bi = (const float*)d_in[2];
    const float* Wf = (const float*)d_in[3];
    const float* bf = (const float*)d_in[4];
    const float* Wo = (const float*)d_in[5];
    const float* bo = (const float*)d_in[6];
    const float* Wu = (const float*)d_in[7];
    const float* bu = (const float*)d_in[8];
    float* out = (float*)d_out;

    unsigned short* xb  = (unsigned short*)d_ws;          // x bf16
    unsigned short* wp  = xb  + 16776704;                 // packed W bf16
    unsigned short* hA  = wp  + 2097152;                  // h ping (16384 rows)
    unsigned short* hB  = hA  + 8388608;                  // h pong ( 8192 rows)
    unsigned short* hs1 = hB  + 4194304;                  // hsum ( 8192 rows)
    unsigned short* hs2 = hs1 + 4194304;                  // hsum ( 4096 rows)
    unsigned short* cA  = hs2 + 2097152;                  // c ping
    unsigned short* cB  = cA  + 8388608;                  // c pong

    // barrier counters overlaid on the dead tail of hA (rows >= 1024 are
    // leaf-only data, dead once level 13 has consumed them)
    unsigned* bar = (unsigned*)(hA + 8388608 - 32);       // 64 B

    pack_w<<<1024, 256, 0, stream>>>(Wi, Wf, Wo, Wu, wp);
    conv_x<<<8192, 256, 0, stream>>>(x, xb);

    leaf_mfma<<<dim3(256, 8), 256, 0, stream>>>(xb, wp, bi, bo, bu, hA, cA, hs1, 16383, 16384);

    for (int lvl = 13; lvl >= 10; --lvl) {
        int cnt   = 1 << lvl;
        int start = cnt - 1;
        const unsigned short *hc, *cc, *hs;
        unsigned short *hw, *cw, *hso;
        if (lvl & 1) { hc = hA; cc = cA; hs = hs1; hw = hB; cw = cB; hso = hs2; }
        else         { hc = hB; cc = cB; hs = hs2; hw = hA; cw = cA; hso = hs1; }
        dim3 grid(cnt / 64, 8);
        level_v2<<<grid, 256, 0, stream>>>(xb, wp, bi, bf, bo, bu,
                                           hc, cc, hs, hw, cw, hso, start, cnt);
    }

    (void)hipMemsetAsync(bar, 0, 64, stream);
    tail_sync<<<TAIL_NBLK, 256, 0, stream>>>(xb, wp, bi, bf, bo, bu,
                                             hA, cA, hB, cB, hs1, hs2, bar, out);
}